// Round 7
// baseline (77.871 us; speedup 1.0000x reference)
//
#include <hip/hip_runtime.h>
#include <hip/hip_bf16.h>
#include <math.h>

using f32x4 = __attribute__((ext_vector_type(4))) float;
using s16x8 = __attribute__((ext_vector_type(8))) short;
using s16x4 = __attribute__((ext_vector_type(4))) short;

#define LOG2E 1.44269504f

__device__ __forceinline__ unsigned short f2bf(float f) {
  unsigned int u = __builtin_bit_cast(unsigned int, f);
  u += 0x7FFFu + ((u >> 16) & 1u);
  return (unsigned short)(u >> 16);
}
__device__ __forceinline__ float lrelu(float v) { return v > 0.f ? v : 0.01f * v; }

// pack two f32 -> one u32 of 2 bf16 (truncation; bias cancels in softmax ratio)
__device__ __forceinline__ unsigned packbf(float lo, float hi) {
  return __builtin_amdgcn_perm(__builtin_bit_cast(unsigned, hi),
                               __builtin_bit_cast(unsigned, lo), 0x07060302u);
}
// reduce (max / sum) across the 4 lh groups (l15 preserved) — shfl butterfly
// (R3-proven; replaces broken tied-register permlane asm from R5/R6).
__device__ __forceinline__ float redmax_lh(float x) {
  x = fmaxf(x, __shfl_xor(x, 16));
  x = fmaxf(x, __shfl_xor(x, 32));
  return x;
}
__device__ __forceinline__ float redsum_lh(float x) {
  x += __shfl_xor(x, 16);
  x += __shfl_xor(x, 32);
  return x;
}
// bit-transposition (lane-bit X <-> register-pair bit): value at (laneX=a,
// reg=B) <-> (laneX=b, reg=A) via butterfly shfl. Element-traced correct.
__device__ __forceinline__ void xswap(unsigned& A, unsigned& B, int X) {
  const int lane = (int)(threadIdx.x & 63);
  unsigned sel = (lane & X) ? A : B;
  unsigned ex = (unsigned)__shfl_xor((int)sel, X);
  A = (lane & X) ? ex : A;
  B = (lane & X) ? B : ex;
}

#define GLL16(src, dst)                                                        \
  __builtin_amdgcn_global_load_lds(                                            \
      (const __attribute__((address_space(1))) void*)(src),                    \
      (__attribute__((address_space(3))) void*)(dst), 16, 0, 0)

// ---------------------------------------------------------------------------
// Kernel 1: x1t[n][c], x2t[n][c] (x2 pre-scaled by log2e), x3[c][n] (bf16)
// grid 512 (b*128 + nchunk32), block 256.
// ---------------------------------------------------------------------------
__global__ __launch_bounds__(256) void k1_conv3(
    const float* __restrict__ x,
    const float* __restrict__ W1, const float* __restrict__ b1,
    const float* __restrict__ W2, const float* __restrict__ b2,
    const float* __restrict__ W3, const float* __restrict__ b3,
    unsigned short* __restrict__ x1t, unsigned short* __restrict__ x2t,
    unsigned short* __restrict__ x3) {
  __shared__ float Wt[3][64][65];
  __shared__ alignas(16) float sX[64][36];
  __shared__ float sB[64][33];
  const int t = threadIdx.x;
  const int b = blockIdx.x >> 7;
  const int n0 = (blockIdx.x & 127) << 5;

  const float* Ws[3] = {W1, W2, W3};
  for (int e = t; e < 12288; e += 256) {
    const int w = e >> 12, idx = e & 4095;
    Wt[w][idx & 63][idx >> 6] = Ws[w][idx];
  }
#pragma unroll
  for (int r = 0; r < 2; ++r) {
    const int idx = t + r * 256;
    const int k = idx >> 3, q = idx & 7;
    *(float4*)&sX[k][q * 4] = *(const float4*)(x + ((size_t)b * 64 + k) * 4096 + n0 + q * 4);
  }
  __syncthreads();

  const int c = t & 63, g = t >> 6;
  float y1[8], y2[8], y3[8];
  const float bb1 = b1[c], bb2 = b2[c], bb3 = b3[c];
#pragma unroll
  for (int j = 0; j < 8; ++j) { y1[j] = bb1; y2[j] = bb2; y3[j] = bb3; }

  for (int k = 0; k < 64; ++k) {
    const float w1 = Wt[0][k][c], w2 = Wt[1][k][c], w3 = Wt[2][k][c];
#pragma unroll
    for (int j = 0; j < 8; ++j) {
      const float xs = sX[k][g * 8 + j];
      y1[j] = __builtin_fmaf(w1, xs, y1[j]);
      y2[j] = __builtin_fmaf(w2, xs, y2[j]);
      y3[j] = __builtin_fmaf(w3, xs, y3[j]);
    }
  }
#pragma unroll
  for (int j = 0; j < 8; ++j) {
    const size_t n = (size_t)n0 + g * 8 + j;
    x1t[((size_t)b * 4096 + n) * 64 + c] = f2bf(lrelu(y1[j]));
    x2t[((size_t)b * 4096 + n) * 64 + c] = f2bf(lrelu(y2[j]) * LOG2E);
    sB[c][g * 8 + j] = lrelu(y3[j]);
  }
  __syncthreads();
  {
    const int c2 = t >> 2, q = t & 3;
    s16x8 v;
#pragma unroll
    for (int jj = 0; jj < 8; ++jj) v[jj] = (short)f2bf(sB[c2][q * 8 + jj]);
    *(s16x8*)(x3 + ((size_t)b * 64 + c2) * 4096 + n0 + q * 8) = v;
  }
}

// ---------------------------------------------------------------------------
// Kernel 2: flash attention + in-block merge + fused conv4/lrelu/residual.
// grid 256 = (b, mtile64). block 1024 = 16 waves = msub(2: 32m) x split(8: 512n).
// Each split: 16 steps of 32n. K,V single-buffered LDS; P transposed in-register
// via two shfl_xor butterfly transpositions.
// Epilogue: fp32 partials -> LDS merge over 8 splits -> W4 conv -> out.
// ---------------------------------------------------------------------------
#define KOFF 0
#define VOFF 32768
#define MLOFF 131072
#define W4OFF 135168
#define SMSZ 152576

__global__ __launch_bounds__(1024) void k2_attn_fused(
    const unsigned short* __restrict__ x1t,
    const unsigned short* __restrict__ x2t,
    const unsigned short* __restrict__ x3,
    const float* __restrict__ W4, const float* __restrict__ b4,
    const float* __restrict__ x, float* __restrict__ out) {
  __shared__ __align__(16) char SM[SMSZ];
  char* smB = (char*)SM;

  const int t = threadIdx.x;
  const int wave = t >> 6, lane = t & 63;
  const int l15 = lane & 15, lh = lane >> 4;
  const int msub = wave & 1, split = wave >> 1; // split 0..7
  const int b = blockIdx.x >> 6;
  const int m0 = (blockIdx.x & 63) << 6;
  const int nb = split * 512;

  const char* x1B = (const char*)(x1t + (size_t)b * 4096 * 64); // [n][c] rows 128B
  const char* x3B = (const char*)(x3 + (size_t)b * 64 * 4096);  // [c][n] rows 8192B
  const unsigned short* x2b = x2t + (size_t)b * 4096 * 64;

  // W4 -> LDS transposed (region disjoint from K/V; loaded once)
  {
    float* Wt4 = (float*)(smB + W4OFF);
    for (int e = t; e < 4096; e += 1024) Wt4[(e & 63) * 68 + (e >> 6)] = W4[e];
  }

  // staging offsets: pre-swizzled global source, linear LDS dest
  int kSrcOff[2], vSrcOff[2];
  char *kDst[2], *vDst[2];
#pragma unroll
  for (int i = 0; i < 2; ++i) {
    const int o = msub * 2048 + i * 1024 + lane * 16;
    {
      const int n = o >> 7, cb = (o & 127) ^ ((n & 7) << 4);
      kSrcOff[i] = n * 128 + cb;
      kDst[i] = smB + KOFF + split * 4096 + msub * 2048 + i * 1024;
    }
    {
      const int ch = o >> 7, rem = (o & 127) ^ ((ch & 7) << 4);
      vSrcOff[i] = (ch * 2 + (rem >> 6)) * 8192 + (rem & 63);
      vDst[i] = smB + VOFF + split * 4096 + msub * 2048 + i * 1024;
    }
  }

  // Q fragments (B-operand), persistent
  s16x8 qf[2][2];
#pragma unroll
  for (int q2 = 0; q2 < 2; ++q2) {
    const unsigned short* qp = x2b + (size_t)(m0 + msub * 32 + q2 * 16 + l15) * 64 + lh * 8;
    qf[q2][0] = *(const s16x8*)qp;
    qf[q2][1] = *(const s16x8*)(qp + 32);
  }

  f32x4 O[2][4];
#pragma unroll
  for (int q2 = 0; q2 < 2; ++q2)
#pragma unroll
    for (int s = 0; s < 4; ++s) O[q2][s] = (f32x4){0.f, 0.f, 0.f, 0.f};
  float m_r[2] = {-INFINITY, -INFINITY}, l_r[2] = {0.f, 0.f};

  const int swzK = (l15 & 7) << 4;
  const int swzV = ((l15 >> 1) & 7) << 4;

  // prologue: stage tile 0
#pragma unroll
  for (int i = 0; i < 2; ++i) {
    GLL16(x1B + (size_t)nb * 128 + kSrcOff[i], kDst[i]);
    GLL16(x3B + (size_t)nb * 2 + vSrcOff[i], vDst[i]);
  }
  __syncthreads();

  for (int j = 0; j < 16; ++j) {
    // ---- LDS fragment reads (K + V for this tile)
    s16x8 kf[2][2], vf[4];
#pragma unroll
    for (int s2 = 0; s2 < 2; ++s2) {
      const char* kp = smB + KOFF + split * 4096 + (s2 * 16 + l15) * 128;
      kf[s2][0] = *(const s16x8*)(kp + ((lh * 16) ^ swzK));
      kf[s2][1] = *(const s16x8*)(kp + ((lh * 16 + 64) ^ swzK));
    }
    const char* vp = smB + VOFF + split * 4096;
#pragma unroll
    for (int s = 0; s < 4; ++s) {
      const int c = s * 16 + l15;
      vf[s] = *(const s16x8*)(vp + (c >> 1) * 128 + (((c & 1) * 64 + lh * 16) ^ swzV));
    }
    // ---- QK: S[q2][s2], n on (s2, lh, r), m on l15
    f32x4 S[2][2];
#pragma unroll
    for (int q2 = 0; q2 < 2; ++q2)
#pragma unroll
      for (int s2 = 0; s2 < 2; ++s2) {
        f32x4 z = {0.f, 0.f, 0.f, 0.f};
        z = __builtin_amdgcn_mfma_f32_16x16x32_bf16(kf[s2][0], qf[q2][0], z, 0, 0, 0);
        S[q2][s2] = __builtin_amdgcn_mfma_f32_16x16x32_bf16(kf[s2][1], qf[q2][1], z, 0, 0, 0);
      }
    __syncthreads(); // all LDS reads retired -> buffers reusable
    if (j < 15) {
      const int nstep = nb + (j + 1) * 32;
#pragma unroll
      for (int i = 0; i < 2; ++i) {
        GLL16(x1B + (size_t)nstep * 128 + kSrcOff[i], kDst[i]);
        GLL16(x3B + (size_t)nstep * 2 + vSrcOff[i], vDst[i]);
      }
    }
    // ---- softmax (base-2, defer-max) + in-register transpose -> pf
    s16x8 pf[2];
#pragma unroll
    for (int q2 = 0; q2 < 2; ++q2) {
      float tmax = fmaxf(fmaxf(fmaxf(S[q2][0][0], S[q2][0][1]), fmaxf(S[q2][0][2], S[q2][0][3])),
                         fmaxf(fmaxf(S[q2][1][0], S[q2][1][1]), fmaxf(S[q2][1][2], S[q2][1][3])));
      tmax = redmax_lh(tmax);
      if (!__all(tmax <= m_r[q2])) {
        const float nm = fmaxf(m_r[q2], tmax);
        const float sc = __builtin_amdgcn_exp2f(m_r[q2] - nm);
        l_r[q2] *= sc;
#pragma unroll
        for (int s = 0; s < 4; ++s) O[q2][s] *= sc;
        m_r[q2] = nm;
      }
      float p[2][4];
      float ts = 0.f;
#pragma unroll
      for (int s2 = 0; s2 < 2; ++s2)
#pragma unroll
        for (int r = 0; r < 4; ++r) {
          p[s2][r] = __builtin_amdgcn_exp2f(S[q2][s2][r] - m_r[q2]);
          ts += p[s2][r];
        }
      l_r[q2] += redsum_lh(ts);
      // pack to bf16 pairs: word u_{s2,rhi}, halves = r-low; then 3-cycle
      // (L5,L4,W1): (n3,n2,n4) -> (n4,n3,n2) via (L5<->W1) then (L4<->W1).
      unsigned u00 = packbf(p[0][0], p[0][1]), u01 = packbf(p[0][2], p[0][3]);
      unsigned u10 = packbf(p[1][0], p[1][1]), u11 = packbf(p[1][2], p[1][3]);
      xswap(u00, u10, 32); xswap(u01, u11, 32); // transposition (L5 <-> W1)
      xswap(u00, u10, 16); xswap(u01, u11, 16); // transposition (L4 <-> W1)
      int4 w = {(int)u00, (int)u01, (int)u10, (int)u11};
      pf[q2] = __builtin_bit_cast(s16x8, w);
    }
    // ---- PV
#pragma unroll
    for (int q2 = 0; q2 < 2; ++q2)
#pragma unroll
      for (int s = 0; s < 4; ++s)
        O[q2][s] = __builtin_amdgcn_mfma_f32_16x16x32_bf16(vf[s], pf[q2], O[q2][s], 0, 0, 0);
    __syncthreads(); // staging drained; next tile ready
  }

  // ---- epilogue 1: publish fp32 partials (overlay on dead K/V region)
  float* cOf = (float*)smB;            // [16][32][64]
  float* sMf = (float*)(smB + MLOFF);  // [16][32]
  float* sLf = sMf + 512;
#pragma unroll
  for (int q2 = 0; q2 < 2; ++q2) {
    const int m32 = q2 * 16 + l15;
    if (lh == 0) { sMf[wave * 32 + m32] = m_r[q2]; sLf[wave * 32 + m32] = l_r[q2]; }
#pragma unroll
    for (int s = 0; s < 4; ++s)
      *(f32x4*)(cOf + wave * 2048 + m32 * 64 + s * 16 + lh * 4) = O[q2][s];
  }
  __syncthreads();

  // ---- epilogue 2: merge 8 splits. thread -> m=t&63, c-quad cq=t>>6
  const int mloc = t & 63, cq = t >> 6;
  const int msub2 = mloc >> 5, m32b = mloc & 31;
  float Mx = -INFINITY;
#pragma unroll
  for (int s2 = 0; s2 < 8; ++s2) Mx = fmaxf(Mx, sMf[(msub2 + 2 * s2) * 32 + m32b]);
  float den = 0.f, num[4] = {0.f, 0.f, 0.f, 0.f};
#pragma unroll
  for (int s2 = 0; s2 < 8; ++s2) {
    const int w = msub2 + 2 * s2;
    const float e = __builtin_amdgcn_exp2f(sMf[w * 32 + m32b] - Mx);
    den += e * sLf[w * 32 + m32b];
    const f32x4 cv = *(const f32x4*)(cOf + w * 2048 + m32b * 64 + cq * 4);
#pragma unroll
    for (int jj = 0; jj < 4; ++jj) num[jj] += e * cv[jj];
  }
  const float inv = 1.f / den;
  __syncthreads(); // cO reads done -> safe to overlay attnS
  float* attnS = (float*)smB; // [64][65]
#pragma unroll
  for (int jj = 0; jj < 4; ++jj) attnS[(cq * 4 + jj) * 65 + mloc] = num[jj] * inv;
  __syncthreads();

  // ---- epilogue 3: out = lrelu(W4 @ attn + b4) + x
  const float* Wt4 = (const float*)(smB + W4OFF); // [64][68]
  const int co0 = cq * 4;
  float acc[4];
#pragma unroll
  for (int ci = 0; ci < 4; ++ci) acc[ci] = b4[co0 + ci];
  for (int k = 0; k < 64; ++k) {
    const float a = attnS[k * 65 + mloc];
    const float4 wv = *(const float4*)&Wt4[k * 68 + co0];
#pragma unroll
    for (int ci = 0; ci < 4; ++ci)
      acc[ci] = __builtin_fmaf(((const float*)&wv)[ci], a, acc[ci]);
  }
#pragma unroll
  for (int ci = 0; ci < 4; ++ci) {
    const size_t idx = ((size_t)b * 64 + co0 + ci) * 4096 + m0 + mloc;
    out[idx] = lrelu(acc[ci]) + x[idx];
  }
}

extern "C" void kernel_launch(void* const* d_in, const int* in_sizes, int n_in,
                              void* d_out, int out_size, void* d_ws, size_t ws_size,
                              hipStream_t stream) {
  const float* x = (const float*)d_in[0];
  const float* W1 = (const float*)d_in[1];
  const float* b1 = (const float*)d_in[2];
  const float* W2 = (const float*)d_in[3];
  const float* b2 = (const float*)d_in[4];
  const float* W3 = (const float*)d_in[5];
  const float* b3 = (const float*)d_in[6];
  const float* W4 = (const float*)d_in[7];
  const float* b4 = (const float*)d_in[8];
  float* out = (float*)d_out;

  const size_t planes = (size_t)4 * 4096 * 64; // 1M bf16 elems each
  unsigned short* x1t = (unsigned short*)d_ws;
  unsigned short* x2t = x1t + planes;
  unsigned short* x3 = x2t + planes;
  // total ws use: 6 MB (<= proven 8 MB budget)

  hipLaunchKernelGGL(k1_conv3, dim3(512), dim3(256), 0, stream,
                     x, W1, b1, W2, b2, W3, b3, x1t, x2t, x3);
  hipLaunchKernelGGL(k2_attn_fused, dim3(256), dim3(1024), 0, stream,
                     x1t, x2t, x3, W4, b4, x, out);
}

// Round 9
// 65.937 us; speedup vs baseline: 1.1810x; 1.1810x over previous
//
#include <hip/hip_runtime.h>
#include <hip/hip_bf16.h>
#include <math.h>

using f32x4 = __attribute__((ext_vector_type(4))) float;
using s16x8 = __attribute__((ext_vector_type(8))) short;
using s16x4 = __attribute__((ext_vector_type(4))) short;

#define LOG2E 1.44269504f

__device__ __forceinline__ unsigned short f2bf(float f) {
  unsigned int u = __builtin_bit_cast(unsigned int, f);
  u += 0x7FFFu + ((u >> 16) & 1u);
  return (unsigned short)(u >> 16);
}
__device__ __forceinline__ float lrelu(float v) { return v > 0.f ? v : 0.01f * v; }

// pack two f32 -> one u32 of 2 bf16 (truncation; bias cancels in softmax ratio)
__device__ __forceinline__ unsigned packbf(float lo, float hi) {
  return __builtin_amdgcn_perm(__builtin_bit_cast(unsigned, hi),
                               __builtin_bit_cast(unsigned, lo), 0x07060302u);
}
// sum across the 4 lh groups (l15 preserved) — used ONCE in epilogue only
__device__ __forceinline__ float redsum_lh(float x) {
  x += __shfl_xor(x, 16);
  x += __shfl_xor(x, 32);
  return x;
}
// bit-transposition (lane-bit X <-> register-pair bit): value at (laneX=a,
// reg=B) <-> (laneX=b, reg=A) via butterfly shfl. R7-PROVEN correct.
// (permlane*_swap asm version computes a DIFFERENT function — R5 vs R6/R7
// A/B evidence; do not reintroduce without an isolated HW-semantics probe.)
__device__ __forceinline__ void xswap(unsigned& A, unsigned& B, int X) {
  const int lane = (int)(threadIdx.x & 63);
  unsigned sel = (lane & X) ? A : B;
  unsigned ex = (unsigned)__shfl_xor((int)sel, X);
  A = (lane & X) ? ex : A;
  B = (lane & X) ? B : ex;
}

#define GLL16(src, dst)                                                        \
  __builtin_amdgcn_global_load_lds(                                            \
      (const __attribute__((address_space(1))) void*)(src),                    \
      (__attribute__((address_space(3))) void*)(dst), 16, 0, 0)

// ---------------------------------------------------------------------------
// Kernel 1: x1t[n][c], x2t[n][c] (x2 pre-scaled by log2e), x3[c][n] (bf16)
// grid 512 (b*128 + nchunk32), block 256.
// ---------------------------------------------------------------------------
__global__ __launch_bounds__(256) void k1_conv3(
    const float* __restrict__ x,
    const float* __restrict__ W1, const float* __restrict__ b1,
    const float* __restrict__ W2, const float* __restrict__ b2,
    const float* __restrict__ W3, const float* __restrict__ b3,
    unsigned short* __restrict__ x1t, unsigned short* __restrict__ x2t,
    unsigned short* __restrict__ x3) {
  __shared__ float Wt[3][64][65];
  __shared__ alignas(16) float sX[64][36];
  __shared__ float sB[64][33];
  const int t = threadIdx.x;
  const int b = blockIdx.x >> 7;
  const int n0 = (blockIdx.x & 127) << 5;

  const float* Ws[3] = {W1, W2, W3};
  for (int e = t; e < 12288; e += 256) {
    const int w = e >> 12, idx = e & 4095;
    Wt[w][idx & 63][idx >> 6] = Ws[w][idx];
  }
#pragma unroll
  for (int r = 0; r < 2; ++r) {
    const int idx = t + r * 256;
    const int k = idx >> 3, q = idx & 7;
    *(float4*)&sX[k][q * 4] = *(const float4*)(x + ((size_t)b * 64 + k) * 4096 + n0 + q * 4);
  }
  __syncthreads();

  const int c = t & 63, g = t >> 6;
  float y1[8], y2[8], y3[8];
  const float bb1 = b1[c], bb2 = b2[c], bb3 = b3[c];
#pragma unroll
  for (int j = 0; j < 8; ++j) { y1[j] = bb1; y2[j] = bb2; y3[j] = bb3; }

  for (int k = 0; k < 64; ++k) {
    const float w1 = Wt[0][k][c], w2 = Wt[1][k][c], w3 = Wt[2][k][c];
#pragma unroll
    for (int j = 0; j < 8; ++j) {
      const float xs = sX[k][g * 8 + j];
      y1[j] = __builtin_fmaf(w1, xs, y1[j]);
      y2[j] = __builtin_fmaf(w2, xs, y2[j]);
      y3[j] = __builtin_fmaf(w3, xs, y3[j]);
    }
  }
#pragma unroll
  for (int j = 0; j < 8; ++j) {
    const size_t n = (size_t)n0 + g * 8 + j;
    x1t[((size_t)b * 4096 + n) * 64 + c] = f2bf(lrelu(y1[j]));
    x2t[((size_t)b * 4096 + n) * 64 + c] = f2bf(lrelu(y2[j]) * LOG2E);
    sB[c][g * 8 + j] = lrelu(y3[j]);
  }
  __syncthreads();
  {
    const int c2 = t >> 2, q = t & 3;
    s16x8 v;
#pragma unroll
    for (int jj = 0; jj < 8; ++jj) v[jj] = (short)f2bf(sB[c2][q * 8 + jj]);
    *(s16x8*)(x3 + ((size_t)b * 64 + c2) * 4096 + n0 + q * 8) = v;
  }
}

// ---------------------------------------------------------------------------
// Kernel 2: flash attention (no-max exp2 softmax) + merge + conv4 + residual.
// grid 256 = (b, mtile64). block 1024 = 16 waves = msub(2: 32m) x split(8: 512n).
// K,V DOUBLE-buffered; ONE barrier per step. P transposed via xswap butterfly
// (R7-proven). l-reduction deferred to epilogue.
// LDS: K 2x32K | V 2x32K | W4 17K | sL 2K; cO overlays K/V exactly.
// ---------------------------------------------------------------------------
#define KOFF 0
#define VOFF 65536
#define W4OFF 131072
#define SLOFF 148480
#define SMSZ 150528

__global__ __launch_bounds__(1024) void k2_attn_fused(
    const unsigned short* __restrict__ x1t,
    const unsigned short* __restrict__ x2t,
    const unsigned short* __restrict__ x3,
    const float* __restrict__ W4, const float* __restrict__ b4,
    const float* __restrict__ x, float* __restrict__ out) {
  __shared__ __align__(16) char SM[SMSZ];
  char* smB = (char*)SM;

  const int t = threadIdx.x;
  const int wave = t >> 6, lane = t & 63;
  const int l15 = lane & 15, lh = lane >> 4;
  const int msub = wave & 1, split = wave >> 1; // split 0..7
  const int b = blockIdx.x >> 6;
  const int m0 = (blockIdx.x & 63) << 6;
  const int nb = split * 512;

  const char* x1B = (const char*)(x1t + (size_t)b * 4096 * 64); // [n][c] rows 128B
  const char* x3B = (const char*)(x3 + (size_t)b * 64 * 4096);  // [c][n] rows 8192B
  const unsigned short* x2b = x2t + (size_t)b * 4096 * 64;

  // W4 -> LDS transposed (region disjoint from K/V; loaded once)
  {
    float* Wt4 = (float*)(smB + W4OFF);
    for (int e = t; e < 4096; e += 1024) Wt4[(e & 63) * 68 + (e >> 6)] = W4[e];
  }

  // staging offsets: pre-swizzled global source, linear LDS dest (base, no p)
  int kSrcOff[2], vSrcOff[2];
  char *kDst[2], *vDst[2];
#pragma unroll
  for (int i = 0; i < 2; ++i) {
    const int o = msub * 2048 + i * 1024 + lane * 16;
    {
      const int n = o >> 7, cb = (o & 127) ^ ((n & 7) << 4);
      kSrcOff[i] = n * 128 + cb;
      kDst[i] = smB + KOFF + split * 4096 + msub * 2048 + i * 1024;
    }
    {
      const int ch = o >> 7, rem = (o & 127) ^ ((ch & 7) << 4);
      vSrcOff[i] = (ch * 2 + (rem >> 6)) * 8192 + (rem & 63);
      vDst[i] = smB + VOFF + split * 4096 + msub * 2048 + i * 1024;
    }
  }

  // Q fragments (B-operand), persistent
  s16x8 qf[2][2];
#pragma unroll
  for (int q2 = 0; q2 < 2; ++q2) {
    const unsigned short* qp = x2b + (size_t)(m0 + msub * 32 + q2 * 16 + l15) * 64 + lh * 8;
    qf[q2][0] = *(const s16x8*)qp;
    qf[q2][1] = *(const s16x8*)(qp + 32);
  }

  f32x4 O[2][4];
#pragma unroll
  for (int q2 = 0; q2 < 2; ++q2)
#pragma unroll
    for (int s = 0; s < 4; ++s) O[q2][s] = (f32x4){0.f, 0.f, 0.f, 0.f};
  float l_part[2] = {0.f, 0.f};

  const int swzK = (l15 & 7) << 4;
  const int swzV = ((l15 >> 1) & 7) << 4;

  // prologue: stage tile 0 into buffer 0
#pragma unroll
  for (int i = 0; i < 2; ++i) {
    GLL16(x1B + (size_t)nb * 128 + kSrcOff[i], kDst[i]);
    GLL16(x3B + (size_t)nb * 2 + vSrcOff[i], vDst[i]);
  }
  __syncthreads();

  for (int j = 0; j < 16; ++j) {
    const int p = j & 1;
    // ---- stage next tile into the other buffer (drained by this step's barrier)
    if (j < 15) {
      const int nstep = nb + (j + 1) * 32;
      const int po = (p ^ 1) * 32768;
#pragma unroll
      for (int i = 0; i < 2; ++i) {
        GLL16(x1B + (size_t)nstep * 128 + kSrcOff[i], kDst[i] + po);
        GLL16(x3B + (size_t)nstep * 2 + vSrcOff[i], vDst[i] + po);
      }
    }
    // ---- LDS fragment reads (K + V for this tile, buffer p)
    s16x8 kf[2][2], vf[4];
#pragma unroll
    for (int s2 = 0; s2 < 2; ++s2) {
      const char* kp = smB + KOFF + p * 32768 + split * 4096 + (s2 * 16 + l15) * 128;
      kf[s2][0] = *(const s16x8*)(kp + ((lh * 16) ^ swzK));
      kf[s2][1] = *(const s16x8*)(kp + ((lh * 16 + 64) ^ swzK));
    }
    const char* vp = smB + VOFF + p * 32768 + split * 4096;
#pragma unroll
    for (int s = 0; s < 4; ++s) {
      const int c = s * 16 + l15;
      vf[s] = *(const s16x8*)(vp + (c >> 1) * 128 + (((c & 1) * 64 + lh * 16) ^ swzV));
    }
    // ---- QK: S[q2][s2], n on (s2, lh, r), m on l15
    f32x4 S[2][2];
#pragma unroll
    for (int q2 = 0; q2 < 2; ++q2)
#pragma unroll
      for (int s2 = 0; s2 < 2; ++s2) {
        f32x4 z = {0.f, 0.f, 0.f, 0.f};
        z = __builtin_amdgcn_mfma_f32_16x16x32_bf16(kf[s2][0], qf[q2][0], z, 0, 0, 0);
        S[q2][s2] = __builtin_amdgcn_mfma_f32_16x16x32_bf16(kf[s2][1], qf[q2][1], z, 0, 0, 0);
      }
    // ---- softmax without max subtraction: p = exp2(S); defer l-reduction
    s16x8 pf[2];
#pragma unroll
    for (int q2 = 0; q2 < 2; ++q2) {
      float pr[2][4];
      float ts = 0.f;
#pragma unroll
      for (int s2 = 0; s2 < 2; ++s2)
#pragma unroll
        for (int r = 0; r < 4; ++r) {
          pr[s2][r] = __builtin_amdgcn_exp2f(S[q2][s2][r]);
          ts += pr[s2][r];
        }
      l_part[q2] += ts; // in-lane partial; lh-reduce deferred to epilogue
      // pack to bf16 pairs then 3-cycle (L5,L4,W1) via PROVEN xswap butterflies
      unsigned u00 = packbf(pr[0][0], pr[0][1]), u01 = packbf(pr[0][2], pr[0][3]);
      unsigned u10 = packbf(pr[1][0], pr[1][1]), u11 = packbf(pr[1][2], pr[1][3]);
      xswap(u00, u10, 32); xswap(u01, u11, 32); // transposition (L5 <-> W1)
      xswap(u00, u10, 16); xswap(u01, u11, 16); // transposition (L4 <-> W1)
      int4 w = {(int)u00, (int)u01, (int)u10, (int)u11};
      pf[q2] = __builtin_bit_cast(s16x8, w);
    }
    // ---- PV
#pragma unroll
    for (int q2 = 0; q2 < 2; ++q2)
#pragma unroll
      for (int s = 0; s < 4; ++s)
        O[q2][s] = __builtin_amdgcn_mfma_f32_16x16x32_bf16(vf[s], pf[q2], O[q2][s], 0, 0, 0);
    __syncthreads(); // one barrier/step: syncs reads of buf p + drains staging
  }

  // ---- epilogue 1: l reduce (once) + publish fp32 partials over dead K/V
  float* cOf = (float*)smB;           // [16][32][64] = 128KB, overlays K+V
  float* sLf = (float*)(smB + SLOFF); // [16][32]
#pragma unroll
  for (int q2 = 0; q2 < 2; ++q2) {
    const float l = redsum_lh(l_part[q2]);
    const int m32 = q2 * 16 + l15;
    if (lh == 0) sLf[wave * 32 + m32] = l;
#pragma unroll
    for (int s = 0; s < 4; ++s)
      *(f32x4*)(cOf + wave * 2048 + m32 * 64 + s * 16 + lh * 4) = O[q2][s];
  }
  __syncthreads();

  // ---- epilogue 2: merge 8 splits (plain sums). thread -> m=t&63, cq=t>>6
  const int mloc = t & 63, cq = t >> 6;
  const int msub2 = mloc >> 5, m32b = mloc & 31;
  float den = 0.f, num[4] = {0.f, 0.f, 0.f, 0.f};
#pragma unroll
  for (int s2 = 0; s2 < 8; ++s2) {
    const int w = msub2 + 2 * s2;
    den += sLf[w * 32 + m32b];
    const f32x4 cv = *(const f32x4*)(cOf + w * 2048 + m32b * 64 + cq * 4);
#pragma unroll
    for (int jj = 0; jj < 4; ++jj) num[jj] += cv[jj];
  }
  const float inv = 1.f / den;
  __syncthreads(); // cO reads done -> safe to overlay attnS
  float* attnS = (float*)smB; // [64][65]
#pragma unroll
  for (int jj = 0; jj < 4; ++jj) attnS[(cq * 4 + jj) * 65 + mloc] = num[jj] * inv;
  __syncthreads();

  // ---- epilogue 3: out = lrelu(W4 @ attn + b4) + x
  const float* Wt4 = (const float*)(smB + W4OFF); // [64][68]
  const int co0 = cq * 4;
  float acc[4];
#pragma unroll
  for (int ci = 0; ci < 4; ++ci) acc[ci] = b4[co0 + ci];
  for (int k = 0; k < 64; ++k) {
    const float a = attnS[k * 65 + mloc];
    const float4 wv = *(const float4*)&Wt4[k * 68 + co0];
#pragma unroll
    for (int ci = 0; ci < 4; ++ci)
      acc[ci] = __builtin_fmaf(((const float*)&wv)[ci], a, acc[ci]);
  }
#pragma unroll
  for (int ci = 0; ci < 4; ++ci) {
    const size_t idx = ((size_t)b * 64 + co0 + ci) * 4096 + m0 + mloc;
    out[idx] = lrelu(acc[ci]) + x[idx];
  }
}

extern "C" void kernel_launch(void* const* d_in, const int* in_sizes, int n_in,
                              void* d_out, int out_size, void* d_ws, size_t ws_size,
                              hipStream_t stream) {
  const float* x = (const float*)d_in[0];
  const float* W1 = (const float*)d_in[1];
  const float* b1 = (const float*)d_in[2];
  const float* W2 = (const float*)d_in[3];
  const float* b2 = (const float*)d_in[4];
  const float* W3 = (const float*)d_in[5];
  const float* b3 = (const float*)d_in[6];
  const float* W4 = (const float*)d_in[7];
  const float* b4 = (const float*)d_in[8];
  float* out = (float*)d_out;

  const size_t planes = (size_t)4 * 4096 * 64; // 1M bf16 elems each
  unsigned short* x1t = (unsigned short*)d_ws;
  unsigned short* x2t = x1t + planes;
  unsigned short* x3 = x2t + planes;
  // total ws use: 6 MB (<= proven 8 MB budget)

  hipLaunchKernelGGL(k1_conv3, dim3(512), dim3(256), 0, stream,
                     x, W1, b1, W2, b2, W3, b3, x1t, x2t, x3);
  hipLaunchKernelGGL(k2_attn_fused, dim3(256), dim3(1024), 0, stream,
                     x1t, x2t, x3, W4, b4, x, out);
}

// Round 10
// 60.720 us; speedup vs baseline: 1.2824x; 1.0859x over previous
//
#include <hip/hip_runtime.h>
#include <hip/hip_bf16.h>
#include <math.h>

using f32x4 = __attribute__((ext_vector_type(4))) float;
using s16x8 = __attribute__((ext_vector_type(8))) short;
using s16x4 = __attribute__((ext_vector_type(4))) short;

#define LOG2E 1.44269504f

__device__ __forceinline__ unsigned short f2bf(float f) {
  unsigned int u = __builtin_bit_cast(unsigned int, f);
  u += 0x7FFFu + ((u >> 16) & 1u);
  return (unsigned short)(u >> 16);
}
__device__ __forceinline__ float lrelu(float v) { return v > 0.f ? v : 0.01f * v; }

// pack two f32 -> one u32 of 2 bf16 (truncation; bias cancels in softmax ratio)
__device__ __forceinline__ unsigned packbf(float lo, float hi) {
  return __builtin_amdgcn_perm(__builtin_bit_cast(unsigned, hi),
                               __builtin_bit_cast(unsigned, lo), 0x07060302u);
}
// sum across the 4 lh groups (l15 preserved) — epilogue only
__device__ __forceinline__ float redsum_lh(float x) {
  x += __shfl_xor(x, 16);
  x += __shfl_xor(x, 32);
  return x;
}
// bit-transposition (lane-bit X <-> register-pair bit). R7/R9-PROVEN.
__device__ __forceinline__ void xswap(unsigned& A, unsigned& B, int X) {
  const int lane = (int)(threadIdx.x & 63);
  unsigned sel = (lane & X) ? A : B;
  unsigned ex = (unsigned)__shfl_xor((int)sel, X);
  A = (lane & X) ? ex : A;
  B = (lane & X) ? B : ex;
}

#define GLL16(src, dst)                                                        \
  __builtin_amdgcn_global_load_lds(                                            \
      (const __attribute__((address_space(1))) void*)(src),                    \
      (__attribute__((address_space(3))) void*)(dst), 16, 0, 0)

// ---------------------------------------------------------------------------
// Kernel 1: x1t[n][c], x2t[n][c] (x2 pre-scaled by log2e), x3[c][n] (bf16)
// grid 512 (b*128 + nchunk32), block 256.  (unchanged from R9)
// ---------------------------------------------------------------------------
__global__ __launch_bounds__(256) void k1_conv3(
    const float* __restrict__ x,
    const float* __restrict__ W1, const float* __restrict__ b1,
    const float* __restrict__ W2, const float* __restrict__ b2,
    const float* __restrict__ W3, const float* __restrict__ b3,
    unsigned short* __restrict__ x1t, unsigned short* __restrict__ x2t,
    unsigned short* __restrict__ x3) {
  __shared__ float Wt[3][64][65];
  __shared__ alignas(16) float sX[64][36];
  __shared__ float sB[64][33];
  const int t = threadIdx.x;
  const int b = blockIdx.x >> 7;
  const int n0 = (blockIdx.x & 127) << 5;

  const float* Ws[3] = {W1, W2, W3};
  for (int e = t; e < 12288; e += 256) {
    const int w = e >> 12, idx = e & 4095;
    Wt[w][idx & 63][idx >> 6] = Ws[w][idx];
  }
#pragma unroll
  for (int r = 0; r < 2; ++r) {
    const int idx = t + r * 256;
    const int k = idx >> 3, q = idx & 7;
    *(float4*)&sX[k][q * 4] = *(const float4*)(x + ((size_t)b * 64 + k) * 4096 + n0 + q * 4);
  }
  __syncthreads();

  const int c = t & 63, g = t >> 6;
  float y1[8], y2[8], y3[8];
  const float bb1 = b1[c], bb2 = b2[c], bb3 = b3[c];
#pragma unroll
  for (int j = 0; j < 8; ++j) { y1[j] = bb1; y2[j] = bb2; y3[j] = bb3; }

  for (int k = 0; k < 64; ++k) {
    const float w1 = Wt[0][k][c], w2 = Wt[1][k][c], w3 = Wt[2][k][c];
#pragma unroll
    for (int j = 0; j < 8; ++j) {
      const float xs = sX[k][g * 8 + j];
      y1[j] = __builtin_fmaf(w1, xs, y1[j]);
      y2[j] = __builtin_fmaf(w2, xs, y2[j]);
      y3[j] = __builtin_fmaf(w3, xs, y3[j]);
    }
  }
#pragma unroll
  for (int j = 0; j < 8; ++j) {
    const size_t n = (size_t)n0 + g * 8 + j;
    x1t[((size_t)b * 4096 + n) * 64 + c] = f2bf(lrelu(y1[j]));
    x2t[((size_t)b * 4096 + n) * 64 + c] = f2bf(lrelu(y2[j]) * LOG2E);
    sB[c][g * 8 + j] = lrelu(y3[j]);
  }
  __syncthreads();
  {
    const int c2 = t >> 2, q = t & 3;
    s16x8 v;
#pragma unroll
    for (int jj = 0; jj < 8; ++jj) v[jj] = (short)f2bf(sB[c2][q * 8 + jj]);
    *(s16x8*)(x3 + ((size_t)b * 64 + c2) * 4096 + n0 + q * 8) = v;
  }
}

// ---------------------------------------------------------------------------
// Kernel 2: flash attention, WAVE-PRIVATE K/V staging, NO loop barriers.
// grid 256 = (b, mtile64). block 512 = 8 waves; wave w owns ALL 64 m and
// n in [w*512,(w+1)*512), 16 steps of 32n. Per-wave double-buffered K/V
// (16KB/wave); pipeline via counted s_waitcnt vmcnt(8) (T4). P transposed
// in-register (xswap). Epilogue: cO[w][c][m] publish -> merge -> conv4+res.
// LDS: waves 8x16K = 128K main loop; epilogue overlay cO [8][64][65] f32
// (133120B) | W4 [64][68] f32 @133120 | sL @150528 (2K). SMSZ=152576.
// ---------------------------------------------------------------------------
#define W4OFF 133120
#define SLOFF 150528
#define SMSZ 152576

__global__ __launch_bounds__(512, 2) void k2_attn_fused(
    const unsigned short* __restrict__ x1t,
    const unsigned short* __restrict__ x2t,
    const unsigned short* __restrict__ x3,
    const float* __restrict__ W4, const float* __restrict__ b4,
    const float* __restrict__ x, float* __restrict__ out) {
  __shared__ __align__(16) char SM[SMSZ];
  char* smB = (char*)SM;

  const int t = threadIdx.x;
  const int wave = t >> 6, lane = t & 63;
  const int l15 = lane & 15, lh = lane >> 4;
  const int b = blockIdx.x >> 6;
  const int m0 = (blockIdx.x & 63) << 6;
  const int nb = wave * 512; // this wave's private n-slice

  const char* x1B = (const char*)(x1t + (size_t)b * 4096 * 64); // [n][c] 128B rows
  const char* x3B = (const char*)(x3 + (size_t)b * 64 * 4096);  // [c][n] 8192B rows
  const unsigned short* x2b = x2t + (size_t)b * 4096 * 64;

  // W4 -> LDS transposed (disjoint region, read only in epilogue)
  {
    float* Wt4 = (float*)(smB + W4OFF);
    for (int e = t; e < 4096; e += 512) Wt4[(e & 63) * 68 + (e >> 6)] = W4[e];
  }

  // wave-private LDS: K at wbase+{0,4096}, V at wbase+8192+{0,4096}
  char* wK = smB + wave * 16384;
  char* wV = wK + 8192;

  // staging source offsets (pre-swizzled global source, linear LDS dest)
  int kSrcOff[4], vSrcOff[4];
#pragma unroll
  for (int i = 0; i < 4; ++i) {
    const int o = i * 1024 + lane * 16;
    {
      const int n = o >> 7, cb = (o & 127) ^ ((n & 7) << 4);
      kSrcOff[i] = n * 128 + cb;
    }
    {
      const int ch = o >> 7, rem = (o & 127) ^ ((ch & 7) << 4);
      vSrcOff[i] = (ch * 2 + (rem >> 6)) * 8192 + (rem & 63);
    }
  }

  // Q fragments (B-operand), persistent: 4 groups of 16 m
  s16x8 qf[4][2];
#pragma unroll
  for (int q2 = 0; q2 < 4; ++q2) {
    const unsigned short* qp = x2b + (size_t)(m0 + q2 * 16 + l15) * 64 + lh * 8;
    qf[q2][0] = *(const s16x8*)qp;
    qf[q2][1] = *(const s16x8*)(qp + 32);
  }

  f32x4 O[4][4];
#pragma unroll
  for (int q2 = 0; q2 < 4; ++q2)
#pragma unroll
    for (int s = 0; s < 4; ++s) O[q2][s] = (f32x4){0.f, 0.f, 0.f, 0.f};
  float l_part[4] = {0.f, 0.f, 0.f, 0.f};

  const int swzK = (l15 & 7) << 4;
  const int swzV = ((l15 >> 1) & 7) << 4;

  // prologue: stage tile 0 into buffer 0
#pragma unroll
  for (int i = 0; i < 4; ++i) GLL16(x1B + (size_t)nb * 128 + kSrcOff[i], wK + i * 1024);
#pragma unroll
  for (int i = 0; i < 4; ++i) GLL16(x3B + (size_t)nb * 2 + vSrcOff[i], wV + i * 1024);

  for (int j = 0; j < 16; ++j) {
    const int p = j & 1;
    // ---- stage next tile into other buffer; counted wait for current tile
    if (j < 15) {
      const int tb = nb + (j + 1) * 32;
      const int po = (p ^ 1) * 4096;
#pragma unroll
      for (int i = 0; i < 4; ++i) GLL16(x1B + (size_t)tb * 128 + kSrcOff[i], wK + po + i * 1024);
#pragma unroll
      for (int i = 0; i < 4; ++i) GLL16(x3B + (size_t)tb * 2 + vSrcOff[i], wV + po + i * 1024);
      asm volatile("s_waitcnt vmcnt(8)" ::: "memory"); // 8 newest (next tile) may fly
    } else {
      asm volatile("s_waitcnt vmcnt(0)" ::: "memory"); // drain last tile
    }
    __builtin_amdgcn_sched_barrier(0); // rule-18 guard: nothing hoists above wait
    // ---- LDS fragment reads (wave-private, no barrier needed)
    s16x8 kf[2][2], vf[4];
#pragma unroll
    for (int s2 = 0; s2 < 2; ++s2) {
      const char* kp = wK + p * 4096 + (s2 * 16 + l15) * 128;
      kf[s2][0] = *(const s16x8*)(kp + ((lh * 16) ^ swzK));
      kf[s2][1] = *(const s16x8*)(kp + ((lh * 16 + 64) ^ swzK));
    }
    const char* vp = wV + p * 4096;
#pragma unroll
    for (int s = 0; s < 4; ++s) {
      const int c = s * 16 + l15;
      vf[s] = *(const s16x8*)(vp + (c >> 1) * 128 + (((c & 1) * 64 + lh * 16) ^ swzV));
    }
    // ---- QK + softmax + transpose + PV, per 16-m group
#pragma unroll
    for (int q2 = 0; q2 < 4; ++q2) {
      f32x4 S[2];
#pragma unroll
      for (int s2 = 0; s2 < 2; ++s2) {
        f32x4 z = {0.f, 0.f, 0.f, 0.f};
        z = __builtin_amdgcn_mfma_f32_16x16x32_bf16(kf[s2][0], qf[q2][0], z, 0, 0, 0);
        S[s2] = __builtin_amdgcn_mfma_f32_16x16x32_bf16(kf[s2][1], qf[q2][1], z, 0, 0, 0);
      }
      float pr[2][4];
      float ts = 0.f;
#pragma unroll
      for (int s2 = 0; s2 < 2; ++s2)
#pragma unroll
        for (int r = 0; r < 4; ++r) {
          pr[s2][r] = __builtin_amdgcn_exp2f(S[s2][r]);
          ts += pr[s2][r];
        }
      l_part[q2] += ts;
      unsigned u00 = packbf(pr[0][0], pr[0][1]), u01 = packbf(pr[0][2], pr[0][3]);
      unsigned u10 = packbf(pr[1][0], pr[1][1]), u11 = packbf(pr[1][2], pr[1][3]);
      xswap(u00, u10, 32); xswap(u01, u11, 32); // (L5 <-> W1)
      xswap(u00, u10, 16); xswap(u01, u11, 16); // (L4 <-> W1)
      int4 w = {(int)u00, (int)u01, (int)u10, (int)u11};
      s16x8 pf = __builtin_bit_cast(s16x8, w);
#pragma unroll
      for (int s = 0; s < 4; ++s)
        O[q2][s] = __builtin_amdgcn_mfma_f32_16x16x32_bf16(vf[s], pf, O[q2][s], 0, 0, 0);
    }
  }

  // ---- epilogue: publish over dead K/V (barrier first: cO[w] spans others' K/V)
  __syncthreads();
  float* cOf = (float*)smB;           // [8][64c][65m] = 133120B
  float* sLf = (float*)(smB + SLOFF); // [8][64]
#pragma unroll
  for (int q2 = 0; q2 < 4; ++q2) {
    const float l = redsum_lh(l_part[q2]);
    if (lh == 0) sLf[wave * 64 + q2 * 16 + l15] = l;
    float* cw = cOf + wave * 4160 + q2 * 16 + l15; // + c*65
#pragma unroll
    for (int s = 0; s < 4; ++s)
#pragma unroll
      for (int r = 0; r < 4; ++r)
        cw[(s * 16 + lh * 4 + r) * 65] = O[q2][s][r];
  }
  __syncthreads();

  // ---- merge 8 n-slices: thread -> m=t&63, channel group cg=t>>6 (8 ch)
  const int mloc = t & 63, cg = t >> 6;
  float den = 0.f;
#pragma unroll
  for (int w = 0; w < 8; ++w) den += sLf[w * 64 + mloc];
  float num[8] = {0.f, 0.f, 0.f, 0.f, 0.f, 0.f, 0.f, 0.f};
#pragma unroll
  for (int w = 0; w < 8; ++w) {
    const float* cw = cOf + w * 4160 + mloc;
#pragma unroll
    for (int jj = 0; jj < 8; ++jj) num[jj] += cw[(cg * 8 + jj) * 65];
  }
  const float inv = 1.f / den;
  __syncthreads(); // cO reads done -> safe to overlay attnS
  float* attnS = (float*)smB; // [64][65]
#pragma unroll
  for (int jj = 0; jj < 8; ++jj) attnS[(cg * 8 + jj) * 65 + mloc] = num[jj] * inv;
  __syncthreads();

  // ---- conv4 + lrelu + residual
  const float* Wt4 = (const float*)(smB + W4OFF); // [64][68]
  const int co0 = cg * 8;
  float acc[8];
#pragma unroll
  for (int ci = 0; ci < 8; ++ci) acc[ci] = b4[co0 + ci];
  for (int k = 0; k < 64; ++k) {
    const float a = attnS[k * 65 + mloc];
    const float4 w0 = *(const float4*)&Wt4[k * 68 + co0];
    const float4 w1 = *(const float4*)&Wt4[k * 68 + co0 + 4];
#pragma unroll
    for (int ci = 0; ci < 4; ++ci) {
      acc[ci] = __builtin_fmaf(((const float*)&w0)[ci], a, acc[ci]);
      acc[ci + 4] = __builtin_fmaf(((const float*)&w1)[ci], a, acc[ci + 4]);
    }
  }
#pragma unroll
  for (int ci = 0; ci < 8; ++ci) {
    const size_t idx = ((size_t)b * 64 + co0 + ci) * 4096 + m0 + mloc;
    out[idx] = lrelu(acc[ci]) + x[idx];
  }
}

extern "C" void kernel_launch(void* const* d_in, const int* in_sizes, int n_in,
                              void* d_out, int out_size, void* d_ws, size_t ws_size,
                              hipStream_t stream) {
  const float* x = (const float*)d_in[0];
  const float* W1 = (const float*)d_in[1];
  const float* b1 = (const float*)d_in[2];
  const float* W2 = (const float*)d_in[3];
  const float* b2 = (const float*)d_in[4];
  const float* W3 = (const float*)d_in[5];
  const float* b3 = (const float*)d_in[6];
  const float* W4 = (const float*)d_in[7];
  const float* b4 = (const float*)d_in[8];
  float* out = (float*)d_out;

  const size_t planes = (size_t)4 * 4096 * 64; // 1M bf16 elems each
  unsigned short* x1t = (unsigned short*)d_ws;
  unsigned short* x2t = x1t + planes;
  unsigned short* x3 = x2t + planes;
  // total ws use: 6 MB (<= proven 8 MB budget)

  hipLaunchKernelGGL(k1_conv3, dim3(512), dim3(256), 0, stream,
                     x, W1, b1, W2, b2, W3, b3, x1t, x2t, x3);
  hipLaunchKernelGGL(k2_attn_fused, dim3(256), dim3(512), 0, stream,
                     x1t, x2t, x3, W4, b4, x, out);
}